// Round 1
// baseline (337.922 us; speedup 1.0000x reference)
//
#include <hip/hip_runtime.h>

// Problem constants (fixed by the reference): N=16384 rows, K=64 clusters, F=2048 features.
#define NROWS 16384
#define KC 64
#define FDIM 2048
#define F4 (FDIM / 4)   // 512 float4 per row
#define ALPHA 1.0f
#define GAMMA 1.0f
#define ROWS_PER_BLK 16

// ---------------------------------------------------------------------------
// K1: per-row argmax of one-hot labels (wave per row) + cluster histogram.
// ---------------------------------------------------------------------------
__global__ __launch_bounds__(256) void k_argmax_hist(
    const float* __restrict__ labels, int* __restrict__ idx, int* __restrict__ counts) {
    int row  = blockIdx.x * 4 + (threadIdx.x >> 6);
    int lane = threadIdx.x & 63;
    float v  = labels[row * KC + lane];
    int best = lane;
    #pragma unroll
    for (int off = 32; off >= 1; off >>= 1) {
        float ov = __shfl_down(v, off);
        int   oi = __shfl_down(best, off);
        if (ov > v) { v = ov; best = oi; }
    }
    if (lane == 0) {
        idx[row] = best;
        atomicAdd(&counts[best], 1);
    }
}

// ---------------------------------------------------------------------------
// K2: row_sum[k] = sum_j ||c_k - c_j||^2 ; then inv_denom[k], scale[k].
// One block per k. Cluster (0.5 MB) is L2-resident.
// ---------------------------------------------------------------------------
__global__ __launch_bounds__(256) void k_rowsum(
    const float* __restrict__ cluster, const float* __restrict__ cw,
    float* __restrict__ inv_denom, float* __restrict__ scale) {
    int k = blockIdx.x, t = threadIdx.x;
    const float4* c4 = (const float4*)cluster;
    float4 a0 = c4[k * F4 + t];
    float4 a1 = c4[k * F4 + 256 + t];
    float acc = 0.f;
    for (int j = 0; j < KC; ++j) {
        float4 b0 = c4[j * F4 + t];
        float4 b1 = c4[j * F4 + 256 + t];
        float d;
        d = a0.x - b0.x; acc += d * d;
        d = a0.y - b0.y; acc += d * d;
        d = a0.z - b0.z; acc += d * d;
        d = a0.w - b0.w; acc += d * d;
        d = a1.x - b1.x; acc += d * d;
        d = a1.y - b1.y; acc += d * d;
        d = a1.z - b1.z; acc += d * d;
        d = a1.w - b1.w; acc += d * d;
    }
    #pragma unroll
    for (int off = 32; off >= 1; off >>= 1) acc += __shfl_down(acc, off);
    __shared__ float red[4];
    if ((t & 63) == 0) red[t >> 6] = acc;
    __syncthreads();
    if (t == 0) {
        float denom = red[0] + red[1] + red[2] + red[3] + ALPHA;
        inv_denom[k] = 1.0f / denom;
        scale[k]     = cw[k] / denom;
    }
}

// ---------------------------------------------------------------------------
// K3: exclusive prefix sum of counts (K=64, trivial single-thread).
// ---------------------------------------------------------------------------
__global__ void k_prefix(const int* __restrict__ counts, int* __restrict__ offsets) {
    if (threadIdx.x == 0) {
        int acc = 0;
        for (int k = 0; k < KC; ++k) { offsets[k] = acc; acc += counts[k]; }
    }
}

// ---------------------------------------------------------------------------
// K4: scatter row ids into cluster-sorted order.
// ---------------------------------------------------------------------------
__global__ __launch_bounds__(256) void k_scatter(
    const int* __restrict__ idx, const int* __restrict__ offsets,
    int* __restrict__ cursor, int* __restrict__ order) {
    int n = blockIdx.x * 256 + threadIdx.x;
    int k = idx[n];
    int p = atomicAdd(&cursor[k], 1);
    order[offsets[k] + p] = n;
}

// ---------------------------------------------------------------------------
// K5: fused main pass. Each block handles ROWS_PER_BLK sorted rows:
//  - loss numerator ||x - c_k||^2 (deferred block reduction through LDS)
//  - per-cluster feature sums in registers, flushed to global delta[] with
//    atomics only at cluster boundaries (sorted order => ~1 flush/block).
// Features (134 MB) are read exactly once here.
// ---------------------------------------------------------------------------
__global__ __launch_bounds__(256) void k_main(
    const float* __restrict__ features, const float* __restrict__ cluster,
    const int* __restrict__ idx, const int* __restrict__ order,
    const float* __restrict__ inv_denom, float* __restrict__ delta,
    float* __restrict__ loss) {
    int t = threadIdx.x;
    __shared__ float part[ROWS_PER_BLK][256];
    const float4* f4 = (const float4*)features;
    const float4* c4 = (const float4*)cluster;
    int base  = blockIdx.x * ROWS_PER_BLK;
    int cur_k = -1;
    float4 s0 = {0.f, 0.f, 0.f, 0.f}, s1 = {0.f, 0.f, 0.f, 0.f};
    float4 c0 = s0, c1 = s1;

    for (int r = 0; r < ROWS_PER_BLK; ++r) {
        int n = order[base + r];          // uniform across block
        int k = idx[n];                   // uniform across block
        if (k != cur_k) {                 // wave-uniform branch
            if (cur_k >= 0) {
                float* dk = delta + cur_k * FDIM;
                atomicAdd(&dk[t * 4 + 0], s0.x);
                atomicAdd(&dk[t * 4 + 1], s0.y);
                atomicAdd(&dk[t * 4 + 2], s0.z);
                atomicAdd(&dk[t * 4 + 3], s0.w);
                atomicAdd(&dk[1024 + t * 4 + 0], s1.x);
                atomicAdd(&dk[1024 + t * 4 + 1], s1.y);
                atomicAdd(&dk[1024 + t * 4 + 2], s1.z);
                atomicAdd(&dk[1024 + t * 4 + 3], s1.w);
                s0.x = s0.y = s0.z = s0.w = 0.f;
                s1.x = s1.y = s1.z = s1.w = 0.f;
            }
            c0 = c4[k * F4 + t];
            c1 = c4[k * F4 + 256 + t];
            cur_k = k;
        }
        float4 x0 = f4[(size_t)n * F4 + t];
        float4 x1 = f4[(size_t)n * F4 + 256 + t];
        s0.x += x0.x; s0.y += x0.y; s0.z += x0.z; s0.w += x0.w;
        s1.x += x1.x; s1.y += x1.y; s1.z += x1.z; s1.w += x1.w;
        float d, p = 0.f;
        d = x0.x - c0.x; p += d * d;
        d = x0.y - c0.y; p += d * d;
        d = x0.z - c0.z; p += d * d;
        d = x0.w - c0.w; p += d * d;
        d = x1.x - c1.x; p += d * d;
        d = x1.y - c1.y; p += d * d;
        d = x1.z - c1.z; p += d * d;
        d = x1.w - c1.w; p += d * d;
        part[r][t] = p;
    }
    // final flush (cur_k always valid: ROWS_PER_BLK >= 1)
    {
        float* dk = delta + cur_k * FDIM;
        atomicAdd(&dk[t * 4 + 0], s0.x);
        atomicAdd(&dk[t * 4 + 1], s0.y);
        atomicAdd(&dk[t * 4 + 2], s0.z);
        atomicAdd(&dk[t * 4 + 3], s0.w);
        atomicAdd(&dk[1024 + t * 4 + 0], s1.x);
        atomicAdd(&dk[1024 + t * 4 + 1], s1.y);
        atomicAdd(&dk[1024 + t * 4 + 2], s1.z);
        atomicAdd(&dk[1024 + t * 4 + 3], s1.w);
    }
    __syncthreads();
    // deferred per-row reductions: wave w handles rows w, w+4, ...
    int w = t >> 6, l = t & 63;
    for (int r = w; r < ROWS_PER_BLK; r += 4) {
        float v = part[r][l] + part[r][l + 64] + part[r][l + 128] + part[r][l + 192];
        #pragma unroll
        for (int off = 32; off >= 1; off >>= 1) v += __shfl_down(v, off);
        if (l == 0) {
            int n = order[base + r];
            loss[n] = v * inv_denom[idx[n]];
        }
    }
}

// ---------------------------------------------------------------------------
// K6: finalize cluster update:
//   new_c[k,f] = c[k,f] - GAMMA * scale[k] * (delta[k,f] - count[k]*c[k,f])
// ---------------------------------------------------------------------------
__global__ __launch_bounds__(256) void k_finalize(
    const float* __restrict__ cluster, const float* __restrict__ delta,
    const int* __restrict__ counts, const float* __restrict__ scale,
    float* __restrict__ outc) {
    int e = blockIdx.x * 256 + threadIdx.x;   // float4 index over KC*F4 = 32768
    int k = e >> 9;                           // / F4
    const float4* c4 = (const float4*)cluster;
    const float4* d4 = (const float4*)delta;
    float4 c = c4[e], d = d4[e];
    float s = scale[k], cnt = (float)counts[k];
    float4 o;
    o.x = c.x - GAMMA * s * (d.x - cnt * c.x);
    o.y = c.y - GAMMA * s * (d.y - cnt * c.y);
    o.z = c.z - GAMMA * s * (d.z - cnt * c.z);
    o.w = c.w - GAMMA * s * (d.w - cnt * c.w);
    ((float4*)outc)[e] = o;
}

extern "C" void kernel_launch(void* const* d_in, const int* in_sizes, int n_in,
                              void* d_out, int out_size, void* d_ws, size_t ws_size,
                              hipStream_t stream) {
    const float* features = (const float*)d_in[0];   // [N, F]
    const float* labels   = (const float*)d_in[1];   // [N, K]
    const float* cluster  = (const float*)d_in[2];   // [K, F]
    const float* cw       = (const float*)d_in[3];   // [K]
    float* loss = (float*)d_out;                     // [N]
    float* outc = (float*)d_out + NROWS;             // [K, F]

    // Workspace layout (all zero-init needed parts at the front):
    char*  ws        = (char*)d_ws;
    float* delta     = (float*)ws;                               // KC*FDIM f32 (512 KB)
    int*   counts    = (int*)(ws + (size_t)KC * FDIM * 4);       // 64
    int*   cursor    = counts + KC;                              // 64
    int*   offsets   = cursor + KC;                              // 64
    float* inv_denom = (float*)(offsets + KC);                   // 64
    float* scale     = inv_denom + KC;                           // 64
    int*   idx       = (int*)(scale + KC);                       // N
    int*   order     = idx + NROWS;                              // N

    // zero delta + counts + cursor
    hipMemsetAsync(d_ws, 0, (size_t)KC * FDIM * 4 + 2 * KC * 4, stream);

    k_argmax_hist<<<NROWS / 4, 256, 0, stream>>>(labels, idx, counts);
    k_rowsum<<<KC, 256, 0, stream>>>(cluster, cw, inv_denom, scale);
    k_prefix<<<1, 64, 0, stream>>>(counts, offsets);
    k_scatter<<<NROWS / 256, 256, 0, stream>>>(idx, offsets, cursor, order);
    k_main<<<NROWS / ROWS_PER_BLK, 256, 0, stream>>>(features, cluster, idx, order,
                                                     inv_denom, delta, loss);
    k_finalize<<<(KC * F4) / 256, 256, 0, stream>>>(cluster, delta, counts, scale, outc);
}

// Round 3
// 228.970 us; speedup vs baseline: 1.4758x; 1.4758x over previous
//
#include <hip/hip_runtime.h>

// Problem constants (fixed by the reference): N=16384 rows, K=64 clusters, F=2048 features.
#define NROWS 16384
#define KC 64
#define FDIM 2048
#define F4 (FDIM / 4)   // 512 float4 per row
#define ALPHA 1.0f
#define GAMMA 1.0f
#define ROWS_PER_BLK 32          // k_main rows per block
#define HB 256                   // histogram blocks (NROWS/64 rows each)
#define ROWS_PER_HB 64           // rows per histogram/scatter block

typedef float f32x4 __attribute__((ext_vector_type(4)));

// ---------------------------------------------------------------------------
// K1: ballot-based argmax of one-hot labels + per-block LDS histogram.
// 256 blocks x 256 threads; each wave handles 16 rows. NO global atomics.
// ---------------------------------------------------------------------------
__global__ __launch_bounds__(256) void k_argmax_hist(
    const float* __restrict__ labels, int* __restrict__ idx,
    int* __restrict__ blockHist) {
    __shared__ int hist[KC];
    int t = threadIdx.x, w = t >> 6, lane = t & 63;
    if (t < KC) hist[t] = 0;
    __syncthreads();
    int rowbase = blockIdx.x * ROWS_PER_HB + w * 16;
    #pragma unroll
    for (int r0 = 0; r0 < 16; r0 += 4) {
        float v0 = labels[(rowbase + r0 + 0) * KC + lane];
        float v1 = labels[(rowbase + r0 + 1) * KC + lane];
        float v2 = labels[(rowbase + r0 + 2) * KC + lane];
        float v3 = labels[(rowbase + r0 + 3) * KC + lane];
        unsigned long long m0 = __ballot(v0 > 0.5f);
        unsigned long long m1 = __ballot(v1 > 0.5f);
        unsigned long long m2 = __ballot(v2 > 0.5f);
        unsigned long long m3 = __ballot(v3 > 0.5f);
        if (lane == 0) {
            int k0 = __ffsll(m0) - 1;
            int k1 = __ffsll(m1) - 1;
            int k2 = __ffsll(m2) - 1;
            int k3 = __ffsll(m3) - 1;
            idx[rowbase + r0 + 0] = k0;
            idx[rowbase + r0 + 1] = k1;
            idx[rowbase + r0 + 2] = k2;
            idx[rowbase + r0 + 3] = k3;
            atomicAdd(&hist[k0], 1);   // LDS atomics: cheap
            atomicAdd(&hist[k1], 1);
            atomicAdd(&hist[k2], 1);
            atomicAdd(&hist[k3], 1);
        }
    }
    __syncthreads();
    if (t < KC) blockHist[blockIdx.x * KC + t] = hist[t];
}

// ---------------------------------------------------------------------------
// K2: single block: per-(block,k) exclusive prefix (blockBase), counts[k],
// global exclusive prefix offsets[k]. 64 KB L2-resident work.
// ---------------------------------------------------------------------------
__global__ __launch_bounds__(64) void k_prefix(
    const int* __restrict__ blockHist, int* __restrict__ blockBase,
    int* __restrict__ counts, int* __restrict__ offsets) {
    int k = threadIdx.x;   // 0..63
    int acc = 0;
    for (int b = 0; b < HB; ++b) {
        int c = blockHist[b * KC + k];
        blockBase[b * KC + k] = acc;
        acc += c;
    }
    counts[k] = acc;
    __shared__ int tot[KC];
    tot[k] = acc;
    __syncthreads();
    if (k == 0) {
        int a = 0;
        for (int j = 0; j < KC; ++j) { offsets[j] = a; a += tot[j]; }
    }
}

// ---------------------------------------------------------------------------
// K3: scatter rows into cluster-sorted order. LDS cursors only.
// 256 blocks x 64 threads, same blocking as K1.
// ---------------------------------------------------------------------------
__global__ __launch_bounds__(64) void k_scatter(
    const int* __restrict__ idx, const int* __restrict__ offsets,
    const int* __restrict__ blockBase, int* __restrict__ order) {
    __shared__ int cur[KC];
    int t = threadIdx.x;
    cur[t] = offsets[t] + blockBase[blockIdx.x * KC + t];
    __syncthreads();
    int n = blockIdx.x * ROWS_PER_HB + t;
    int k = idx[n];
    int p = atomicAdd(&cur[k], 1);   // LDS atomic, <=64-way
    order[p] = n;
}

// ---------------------------------------------------------------------------
// K4: row_sum[k] = sum_j ||c_k - c_j||^2 ; then inv_denom[k], scale[k].
// ---------------------------------------------------------------------------
__global__ __launch_bounds__(256) void k_rowsum(
    const float* __restrict__ cluster, const float* __restrict__ cw,
    float* __restrict__ inv_denom, float* __restrict__ scale) {
    int k = blockIdx.x, t = threadIdx.x;
    const float4* c4 = (const float4*)cluster;
    float4 a0 = c4[k * F4 + t];
    float4 a1 = c4[k * F4 + 256 + t];
    float acc = 0.f;
    for (int j = 0; j < KC; ++j) {
        float4 b0 = c4[j * F4 + t];
        float4 b1 = c4[j * F4 + 256 + t];
        float d;
        d = a0.x - b0.x; acc += d * d;
        d = a0.y - b0.y; acc += d * d;
        d = a0.z - b0.z; acc += d * d;
        d = a0.w - b0.w; acc += d * d;
        d = a1.x - b1.x; acc += d * d;
        d = a1.y - b1.y; acc += d * d;
        d = a1.z - b1.z; acc += d * d;
        d = a1.w - b1.w; acc += d * d;
    }
    #pragma unroll
    for (int off = 32; off >= 1; off >>= 1) acc += __shfl_down(acc, off);
    __shared__ float red[4];
    if ((t & 63) == 0) red[t >> 6] = acc;
    __syncthreads();
    if (t == 0) {
        float denom = red[0] + red[1] + red[2] + red[3] + ALPHA;
        inv_denom[k] = 1.0f / denom;
        scale[k]     = cw[k] / denom;
    }
}

// ---------------------------------------------------------------------------
// K5: fused main pass over sorted rows (512 blocks x 32 rows).
// Features read exactly once (non-temporal). Delta flushed with global
// atomics only at cluster boundaries (~1 flush/block).
// ---------------------------------------------------------------------------
__global__ __launch_bounds__(256) void k_main(
    const float* __restrict__ features, const float* __restrict__ cluster,
    const int* __restrict__ idx, const int* __restrict__ order,
    const float* __restrict__ inv_denom, float* __restrict__ delta,
    float* __restrict__ loss) {
    int t = threadIdx.x;
    __shared__ float part[ROWS_PER_BLK][256];
    __shared__ int onum[ROWS_PER_BLK];
    __shared__ int okk[ROWS_PER_BLK];
    int base = blockIdx.x * ROWS_PER_BLK;
    if (t < ROWS_PER_BLK) {
        int n = order[base + t];
        onum[t] = n;
        okk[t]  = idx[n];
    }
    __syncthreads();

    const f32x4* f4 = (const f32x4*)features;
    const float4* c4 = (const float4*)cluster;
    int cur_k = -1;
    float4 s0 = {0.f, 0.f, 0.f, 0.f}, s1 = {0.f, 0.f, 0.f, 0.f};
    float4 c0 = s0, c1 = s1;

    for (int r = 0; r < ROWS_PER_BLK; ++r) {
        int n = onum[r];                  // uniform, LDS broadcast
        int k = okk[r];
        if (k != cur_k) {                 // wave-uniform, rare
            if (cur_k >= 0) {
                float* dk = delta + cur_k * FDIM;
                atomicAdd(&dk[t * 4 + 0], s0.x);
                atomicAdd(&dk[t * 4 + 1], s0.y);
                atomicAdd(&dk[t * 4 + 2], s0.z);
                atomicAdd(&dk[t * 4 + 3], s0.w);
                atomicAdd(&dk[1024 + t * 4 + 0], s1.x);
                atomicAdd(&dk[1024 + t * 4 + 1], s1.y);
                atomicAdd(&dk[1024 + t * 4 + 2], s1.z);
                atomicAdd(&dk[1024 + t * 4 + 3], s1.w);
                s0.x = s0.y = s0.z = s0.w = 0.f;
                s1.x = s1.y = s1.z = s1.w = 0.f;
            }
            c0 = c4[k * F4 + t];
            c1 = c4[k * F4 + 256 + t];
            cur_k = k;
        }
        f32x4 xv0 = __builtin_nontemporal_load(&f4[(size_t)n * F4 + t]);
        f32x4 xv1 = __builtin_nontemporal_load(&f4[(size_t)n * F4 + 256 + t]);
        float4 x0 = {xv0.x, xv0.y, xv0.z, xv0.w};
        float4 x1 = {xv1.x, xv1.y, xv1.z, xv1.w};
        s0.x += x0.x; s0.y += x0.y; s0.z += x0.z; s0.w += x0.w;
        s1.x += x1.x; s1.y += x1.y; s1.z += x1.z; s1.w += x1.w;
        float d, p = 0.f;
        d = x0.x - c0.x; p += d * d;
        d = x0.y - c0.y; p += d * d;
        d = x0.z - c0.z; p += d * d;
        d = x0.w - c0.w; p += d * d;
        d = x1.x - c1.x; p += d * d;
        d = x1.y - c1.y; p += d * d;
        d = x1.z - c1.z; p += d * d;
        d = x1.w - c1.w; p += d * d;
        part[r][t] = p;
    }
    // final flush
    {
        float* dk = delta + cur_k * FDIM;
        atomicAdd(&dk[t * 4 + 0], s0.x);
        atomicAdd(&dk[t * 4 + 1], s0.y);
        atomicAdd(&dk[t * 4 + 2], s0.z);
        atomicAdd(&dk[t * 4 + 3], s0.w);
        atomicAdd(&dk[1024 + t * 4 + 0], s1.x);
        atomicAdd(&dk[1024 + t * 4 + 1], s1.y);
        atomicAdd(&dk[1024 + t * 4 + 2], s1.z);
        atomicAdd(&dk[1024 + t * 4 + 3], s1.w);
    }
    __syncthreads();
    // deferred per-row reductions: wave w handles rows w, w+4, ...
    int w = t >> 6, l = t & 63;
    for (int r = w; r < ROWS_PER_BLK; r += 4) {
        float v = part[r][l] + part[r][l + 64] + part[r][l + 128] + part[r][l + 192];
        #pragma unroll
        for (int off = 32; off >= 1; off >>= 1) v += __shfl_down(v, off);
        if (l == 0) {
            loss[onum[r]] = v * inv_denom[okk[r]];
        }
    }
}

// ---------------------------------------------------------------------------
// K6: finalize cluster update:
//   new_c[k,f] = c[k,f] - GAMMA * scale[k] * (delta[k,f] - count[k]*c[k,f])
// ---------------------------------------------------------------------------
__global__ __launch_bounds__(256) void k_finalize(
    const float* __restrict__ cluster, const float* __restrict__ delta,
    const int* __restrict__ counts, const float* __restrict__ scale,
    float* __restrict__ outc) {
    int e = blockIdx.x * 256 + threadIdx.x;   // float4 index over KC*F4 = 32768
    int k = e >> 9;                           // / F4
    const float4* c4 = (const float4*)cluster;
    const float4* d4 = (const float4*)delta;
    float4 c = c4[e], d = d4[e];
    float s = scale[k], cnt = (float)counts[k];
    float4 o;
    o.x = c.x - GAMMA * s * (d.x - cnt * c.x);
    o.y = c.y - GAMMA * s * (d.y - cnt * c.y);
    o.z = c.z - GAMMA * s * (d.z - cnt * c.z);
    o.w = c.w - GAMMA * s * (d.w - cnt * c.w);
    ((float4*)outc)[e] = o;
}

extern "C" void kernel_launch(void* const* d_in, const int* in_sizes, int n_in,
                              void* d_out, int out_size, void* d_ws, size_t ws_size,
                              hipStream_t stream) {
    const float* features = (const float*)d_in[0];   // [N, F]
    const float* labels   = (const float*)d_in[1];   // [N, K]
    const float* cluster  = (const float*)d_in[2];   // [K, F]
    const float* cw       = (const float*)d_in[3];   // [K]
    float* loss = (float*)d_out;                     // [N]
    float* outc = (float*)d_out + NROWS;             // [K, F]

    // Workspace layout:
    char*  ws        = (char*)d_ws;
    float* delta     = (float*)ws;                               // KC*FDIM f32 (512 KB) — memset
    int*   counts    = (int*)(ws + (size_t)KC * FDIM * 4);       // 64
    int*   offsets   = counts + KC;                              // 64
    float* inv_denom = (float*)(offsets + KC);                   // 64
    float* scale     = inv_denom + KC;                           // 64
    int*   idx       = (int*)(scale + KC);                       // N
    int*   order     = idx + NROWS;                              // N
    int*   blockHist = order + NROWS;                            // HB*KC = 16384
    int*   blockBase = blockHist + HB * KC;                      // HB*KC = 16384

    // zero only delta (everything else is fully written before read)
    hipMemsetAsync(delta, 0, (size_t)KC * FDIM * 4, stream);

    k_argmax_hist<<<HB, 256, 0, stream>>>(labels, idx, blockHist);
    k_rowsum<<<KC, 256, 0, stream>>>(cluster, cw, inv_denom, scale);
    k_prefix<<<1, 64, 0, stream>>>(blockHist, blockBase, counts, offsets);
    k_scatter<<<HB, 64, 0, stream>>>(idx, offsets, blockBase, order);
    k_main<<<NROWS / ROWS_PER_BLK, 256, 0, stream>>>(features, cluster, idx, order,
                                                     inv_denom, delta, loss);
    k_finalize<<<(KC * F4) / 256, 256, 0, stream>>>(cluster, delta, counts, scale, outc);
}